// Round 2
// baseline (436.447 us; speedup 1.0000x reference)
//
#include <hip/hip_runtime.h>
#include <stdint.h>

// Problem constants (fixed shapes from reference)
#define M_DIM 4096   // 2 * 2048 rows of x
#define K_DIM 4096   // in_features
#define N_DIM 4096   // out_features
#define NUM_SUB (65536 * 8)  // superblocks * 8 subblocks

typedef __bf16 bf16_t;
typedef bf16_t bf16x8 __attribute__((ext_vector_type(8)));
typedef float f32x4 __attribute__((ext_vector_type(4)));

// ---------------------------------------------------------------------------
// Kernel 1: fp32 -> bf16 convert of x (16.7M elements), vectorized 8/thread
// ---------------------------------------------------------------------------
__global__ __launch_bounds__(256) void cvt_x_bf16(const float* __restrict__ x,
                                                  bf16_t* __restrict__ o) {
    size_t i = ((size_t)blockIdx.x * blockDim.x + threadIdx.x) * 8;
    const float4* p = (const float4*)(x + i);
    float4 a = p[0];
    float4 b = p[1];
    bf16x8 v;
    v[0] = (bf16_t)a.x; v[1] = (bf16_t)a.y; v[2] = (bf16_t)a.z; v[3] = (bf16_t)a.w;
    v[4] = (bf16_t)b.x; v[5] = (bf16_t)b.y; v[6] = (bf16_t)b.z; v[7] = (bf16_t)b.w;
    *(bf16x8*)(o + i) = v;
}

// ---------------------------------------------------------------------------
// Kernel 2: Q4_K-style dequant -> bf16 W[N][K].
// Thread t = one subblock (32 weights = 16 packed "bytes" stored as int32).
// w = q * (d*scale/945) + (d*min/63 + dmin)
//   q[2i] = packed[i] & 15 ; q[2i+1] = (packed[i]>>4) & 15
// ---------------------------------------------------------------------------
__global__ __launch_bounds__(256) void dequant_w(const int* __restrict__ packed,
                                                 const float* __restrict__ d,
                                                 const float* __restrict__ dmin,
                                                 const int* __restrict__ scales,
                                                 const int* __restrict__ mins,
                                                 bf16_t* __restrict__ W) {
    int t = blockIdx.x * blockDim.x + threadIdx.x;   // 0 .. NUM_SUB-1
    int s = t >> 3;                                  // superblock
    float ds = d[s];
    float dm = dmin[s];
    float a = ds * (float)scales[t] * (1.0f / 945.0f);   // 945 = 15*63
    float b = ds * (float)mins[t] * (1.0f / 63.0f) + dm;

    const int4* p4 = (const int4*)(packed + (size_t)t * 16);
    bf16_t outv[32];
#pragma unroll
    for (int c = 0; c < 4; ++c) {
        int4 pv = p4[c];
        int vals[4] = {pv.x, pv.y, pv.z, pv.w};
#pragma unroll
        for (int u = 0; u < 4; ++u) {
            int byte = vals[u];
            float lo = (float)(byte & 15) * a + b;
            float hi = (float)((byte >> 4) & 15) * a + b;
            outv[c * 8 + u * 2]     = (bf16_t)lo;
            outv[c * 8 + u * 2 + 1] = (bf16_t)hi;
        }
    }
    bf16_t* dst = W + (size_t)t * 32;
#pragma unroll
    for (int c = 0; c < 4; ++c)
        ((bf16x8*)dst)[c] = ((const bf16x8*)outv)[c];
}

// ---------------------------------------------------------------------------
// Kernel 3: C[M,N] (fp32) = A[M,K](bf16) * B[N,K](bf16)^T  — m97 recipe with
// conflict-free LDS layout: staging order == fragment-read order.
//
// LDS layout: 8 "groups" per operand tile, group g = rows [g*16, g*16+16).
// Group g occupies 1KB at sA + g*512 elems; chunk i (16B) within a group is
// (row = i&15, kchunk = i>>4). Fragment read for MFMA lane = q*16+r is then
// the IDENTITY: lane i reads chunk i  ->  banks 4i..4i+3 mod 32, 2-way/phase
// = conflict-free (m136). Staging lane L therefore fetches global
// (row L&15, kchunk L>>4) of its wave's 16-row group; per-wave global
// segments are still 16 x 64B (coalescing unchanged vs row-major order).
// ---------------------------------------------------------------------------
#define BM 128
#define BN 128
#define BK 32

__device__ __forceinline__ void async_copy16(void* lds, const void* g) {
    __builtin_amdgcn_global_load_lds(
        (const __attribute__((address_space(1))) void*)g,
        (__attribute__((address_space(3))) void*)lds, 16, 0, 0);
}

__global__ __launch_bounds__(256) void gemm_bt(const bf16_t* __restrict__ A,
                                               const bf16_t* __restrict__ B,
                                               float* __restrict__ C) {
    __shared__ bf16_t sA[BM * BK];   // 8 KB
    __shared__ bf16_t sB[BN * BK];   // 8 KB

    const int tid  = threadIdx.x;
    const int wave = tid >> 6;
    const int lane = tid & 63;
    const int wm = wave >> 1;        // wave row (0/1) -> 64 rows of C
    const int wn = wave & 1;         // wave col (0/1) -> 64 cols of C
    const int r = lane & 15;         // MFMA row/col within 16
    const int q = lane >> 4;         // MFMA k-chunk quad (0..3)

    const int n0 = blockIdx.x * BN;
    const int m0 = blockIdx.y * BM;

    f32x4 acc[4][4] = {};

    // Staging source: lane L of wave w fetches (row w*16 + (L&15), kchunk L>>4)
    const int rowS = (tid >> 6) * 16 + (tid & 15);   // 0..63 (call 0); +64 call 1
    const int kcS  = ((tid >> 4) & 3) * 8;           // k element offset
    const bf16_t* gA0 = A + (size_t)(m0 + rowS) * K_DIM + kcS;
    const bf16_t* gA1 = gA0 + (size_t)64 * K_DIM;
    const bf16_t* gB0 = B + (size_t)(n0 + rowS) * K_DIM + kcS;
    const bf16_t* gB1 = gB0 + (size_t)64 * K_DIM;
    // Wave-uniform LDS bases: wave w's group lives at g*512 elems (g = wave,
    // call 0) and (4 + wave)*512 (call 1); builtin adds lane*16B itself.
    bf16_t* lA0 = &sA[wave * 512];
    bf16_t* lA1 = &sA[(4 + wave) * 512];
    bf16_t* lB0 = &sB[wave * 512];
    bf16_t* lB1 = &sB[(4 + wave) * 512];

    for (int k0 = 0; k0 < K_DIM; k0 += BK) {
        if (k0) __syncthreads();             // protect LDS from overwrite
        async_copy16(lA0, gA0 + k0);
        async_copy16(lA1, gA1 + k0);
        async_copy16(lB0, gB0 + k0);
        async_copy16(lB1, gB1 + k0);
        asm volatile("s_waitcnt vmcnt(0)" ::: "memory");
        __syncthreads();

        bf16x8 af[4], bfr[4];
#pragma unroll
        for (int t = 0; t < 4; ++t) {
            // group (wm*4 + t), chunk = lane  (identity -> conflict-free)
            af[t]  = *(const bf16x8*)&sA[(wm * 4 + t) * 512 + lane * 8];
            bfr[t] = *(const bf16x8*)&sB[(wn * 4 + t) * 512 + lane * 8];
        }
#pragma unroll
        for (int i = 0; i < 4; ++i)
#pragma unroll
            for (int j = 0; j < 4; ++j)
                acc[i][j] = __builtin_amdgcn_mfma_f32_16x16x32_bf16(
                    af[i], bfr[j], acc[i][j], 0, 0, 0);
    }

    // Epilogue: C/D layout col = lane&15, row = (lane>>4)*4 + reg  [m89]
#pragma unroll
    for (int i = 0; i < 4; ++i) {
        int row = m0 + wm * 64 + i * 16 + q * 4;
#pragma unroll
        for (int j = 0; j < 4; ++j) {
            int col = n0 + wn * 64 + j * 16 + r;
#pragma unroll
            for (int reg = 0; reg < 4; ++reg)
                C[(size_t)(row + reg) * N_DIM + col] = acc[i][j][reg];
        }
    }
}

// ---------------------------------------------------------------------------
// Launch: needs 67 MB of d_ws (33.5 MB x-bf16 + 33.5 MB W-bf16).
// ---------------------------------------------------------------------------
extern "C" void kernel_launch(void* const* d_in, const int* in_sizes, int n_in,
                              void* d_out, int out_size, void* d_ws, size_t ws_size,
                              hipStream_t stream) {
    const float* x      = (const float*)d_in[0];
    const int*   packed = (const int*)d_in[1];
    const float* d      = (const float*)d_in[2];
    const float* dmin   = (const float*)d_in[3];
    const int*   scales = (const int*)d_in[4];
    const int*   mins   = (const int*)d_in[5];
    float* out = (float*)d_out;

    bf16_t* xb = (bf16_t*)d_ws;                       // [M_DIM * K_DIM]
    bf16_t* wb = xb + (size_t)M_DIM * K_DIM;          // [N_DIM * K_DIM]

    cvt_x_bf16<<<(M_DIM * (size_t)K_DIM) / (256 * 8), 256, 0, stream>>>(x, xb);
    dequant_w<<<NUM_SUB / 256, 256, 0, stream>>>(packed, d, dmin, scales, mins, wb);
    gemm_bt<<<dim3(N_DIM / BN, M_DIM / BM), 256, 0, stream>>>(xb, wb, out);
}

// Round 3
// 330.866 us; speedup vs baseline: 1.3191x; 1.3191x over previous
//
#include <hip/hip_runtime.h>
#include <stdint.h>

// Problem constants (fixed shapes from reference)
#define M_DIM 4096   // 2 * 2048 rows of x
#define K_DIM 4096   // in_features
#define N_DIM 4096   // out_features
#define NUM_SUB (65536 * 8)  // superblocks * 8 subblocks

typedef __bf16 bf16_t;
typedef bf16_t bf16x8 __attribute__((ext_vector_type(8)));
typedef float f32x4 __attribute__((ext_vector_type(4)));

// ---------------------------------------------------------------------------
// Kernel 1: fp32 -> bf16 convert of x (16.7M elements), vectorized 8/thread
// ---------------------------------------------------------------------------
__global__ __launch_bounds__(256) void cvt_x_bf16(const float* __restrict__ x,
                                                  bf16_t* __restrict__ o) {
    size_t i = ((size_t)blockIdx.x * blockDim.x + threadIdx.x) * 8;
    const float4* p = (const float4*)(x + i);
    float4 a = p[0];
    float4 b = p[1];
    bf16x8 v;
    v[0] = (bf16_t)a.x; v[1] = (bf16_t)a.y; v[2] = (bf16_t)a.z; v[3] = (bf16_t)a.w;
    v[4] = (bf16_t)b.x; v[5] = (bf16_t)b.y; v[6] = (bf16_t)b.z; v[7] = (bf16_t)b.w;
    *(bf16x8*)(o + i) = v;
}

// ---------------------------------------------------------------------------
// Kernel 2: Q4_K-style dequant -> bf16 W[N][K].
// w = q * (d*scale/945) + (d*min/63 + dmin)
// ---------------------------------------------------------------------------
__global__ __launch_bounds__(256) void dequant_w(const int* __restrict__ packed,
                                                 const float* __restrict__ d,
                                                 const float* __restrict__ dmin,
                                                 const int* __restrict__ scales,
                                                 const int* __restrict__ mins,
                                                 bf16_t* __restrict__ W) {
    int t = blockIdx.x * blockDim.x + threadIdx.x;   // 0 .. NUM_SUB-1
    int s = t >> 3;                                  // superblock
    float ds = d[s];
    float dm = dmin[s];
    float a = ds * (float)scales[t] * (1.0f / 945.0f);   // 945 = 15*63
    float b = ds * (float)mins[t] * (1.0f / 63.0f) + dm;

    const int4* p4 = (const int4*)(packed + (size_t)t * 16);
    bf16_t outv[32];
#pragma unroll
    for (int c = 0; c < 4; ++c) {
        int4 pv = p4[c];
        int vals[4] = {pv.x, pv.y, pv.z, pv.w};
#pragma unroll
        for (int u = 0; u < 4; ++u) {
            int byte = vals[u];
            float lo = (float)(byte & 15) * a + b;
            float hi = (float)((byte >> 4) & 15) * a + b;
            outv[c * 8 + u * 2]     = (bf16_t)lo;
            outv[c * 8 + u * 2 + 1] = (bf16_t)hi;
        }
    }
    bf16_t* dst = W + (size_t)t * 32;
#pragma unroll
    for (int c = 0; c < 4; ++c)
        ((bf16x8*)dst)[c] = ((const bf16x8*)outv)[c];
}

// ---------------------------------------------------------------------------
// Kernel 3: C[M,N](fp32) = A[M,K](bf16) * B[N,K](bf16)^T
// m97 recipe + XOR-swizzled LDS chunk layout giving BOTH:
//   - coalesced global staging: lanes 4i..4i+3 fetch row i, 64 contiguous B
//     (k-chunk order permuted per row by XOR — completeness preserved)
//   - conflict-free ds_read_b128: phase q reads chunks 4r + (q ^ ((r>>1)&3));
//     residues mod 8 balanced (2 lanes/bank group = free, m136)
// LDS: per operand, 8 groups of 16 rows; group g at offset g*512 elems;
// chunk slot i holds (row i>>2, kc (i&3) ^ ((i>>3)&3)).
// ---------------------------------------------------------------------------
#define BM 128
#define BN 128
#define BK 32

__device__ __forceinline__ void async_copy16(void* lds, const void* g) {
    __builtin_amdgcn_global_load_lds(
        (const __attribute__((address_space(1))) void*)g,
        (__attribute__((address_space(3))) void*)lds, 16, 0, 0);
}

__global__ __launch_bounds__(256) void gemm_bt(const bf16_t* __restrict__ A,
                                               const bf16_t* __restrict__ B,
                                               float* __restrict__ C) {
    __shared__ bf16_t sA[BM * BK];   // 8 KB
    __shared__ bf16_t sB[BN * BK];   // 8 KB

    const int tid  = threadIdx.x;
    const int wave = tid >> 6;
    const int lane = tid & 63;
    const int wm = wave >> 1;        // wave row (0/1) -> 64 rows of C
    const int wn = wave & 1;         // wave col (0/1) -> 64 cols of C
    const int r = lane & 15;         // MFMA row/col within 16
    const int q = lane >> 4;         // MFMA k-chunk quad (0..3)

    const int n0 = blockIdx.x * BN;
    const int m0 = blockIdx.y * BM;

    f32x4 acc[4][4] = {};

    // Staging: lane fetches (row = tid>>2, kc = (lane&3) ^ ((lane>>3)&3)).
    // 4 consecutive lanes cover one row's full 64 B (coalesced).
    const int rowS = tid >> 2;                         // 0..63 (+64 for call 1)
    const int kcS  = ((lane & 3) ^ ((lane >> 3) & 3)) * 8;
    const bf16_t* gA0 = A + (size_t)(m0 + rowS) * K_DIM + kcS;
    const bf16_t* gA1 = gA0 + (size_t)64 * K_DIM;
    const bf16_t* gB0 = B + (size_t)(n0 + rowS) * K_DIM + kcS;
    const bf16_t* gB1 = gB0 + (size_t)64 * K_DIM;
    // Wave-uniform LDS bases (builtin adds lane*16B itself).
    bf16_t* lA0 = &sA[wave * 512];
    bf16_t* lA1 = &sA[(4 + wave) * 512];
    bf16_t* lB0 = &sB[wave * 512];
    bf16_t* lB1 = &sB[(4 + wave) * 512];

    // Fragment-read chunk index for this lane: c = 4r + (q ^ ((r>>1)&3))
    const int fragOff = (4 * r + (q ^ ((r >> 1) & 3))) * 8;   // elements

    for (int k0 = 0; k0 < K_DIM; k0 += BK) {
        if (k0) __syncthreads();             // protect LDS from overwrite
        async_copy16(lA0, gA0 + k0);
        async_copy16(lA1, gA1 + k0);
        async_copy16(lB0, gB0 + k0);
        async_copy16(lB1, gB1 + k0);
        asm volatile("s_waitcnt vmcnt(0)" ::: "memory");
        __syncthreads();

        bf16x8 af[4], bfr[4];
#pragma unroll
        for (int t = 0; t < 4; ++t) {
            af[t]  = *(const bf16x8*)&sA[(wm * 4 + t) * 512 + fragOff];
            bfr[t] = *(const bf16x8*)&sB[(wn * 4 + t) * 512 + fragOff];
        }
#pragma unroll
        for (int i = 0; i < 4; ++i)
#pragma unroll
            for (int j = 0; j < 4; ++j)
                acc[i][j] = __builtin_amdgcn_mfma_f32_16x16x32_bf16(
                    af[i], bfr[j], acc[i][j], 0, 0, 0);
    }

    // Epilogue: C/D layout col = lane&15, row = (lane>>4)*4 + reg  [m89]
#pragma unroll
    for (int i = 0; i < 4; ++i) {
        int row = m0 + wm * 64 + i * 16 + q * 4;
#pragma unroll
        for (int j = 0; j < 4; ++j) {
            int col = n0 + wn * 64 + j * 16 + r;
#pragma unroll
            for (int reg = 0; reg < 4; ++reg)
                C[(size_t)(row + reg) * N_DIM + col] = acc[i][j][reg];
        }
    }
}

// ---------------------------------------------------------------------------
// Launch: needs 67 MB of d_ws (33.5 MB x-bf16 + 33.5 MB W-bf16).
// ---------------------------------------------------------------------------
extern "C" void kernel_launch(void* const* d_in, const int* in_sizes, int n_in,
                              void* d_out, int out_size, void* d_ws, size_t ws_size,
                              hipStream_t stream) {
    const float* x      = (const float*)d_in[0];
    const int*   packed = (const int*)d_in[1];
    const float* d      = (const float*)d_in[2];
    const float* dmin   = (const float*)d_in[3];
    const int*   scales = (const int*)d_in[4];
    const int*   mins   = (const int*)d_in[5];
    float* out = (float*)d_out;

    bf16_t* xb = (bf16_t*)d_ws;                       // [M_DIM * K_DIM]
    bf16_t* wb = xb + (size_t)M_DIM * K_DIM;          // [N_DIM * K_DIM]

    cvt_x_bf16<<<(M_DIM * (size_t)K_DIM) / (256 * 8), 256, 0, stream>>>(x, xb);
    dequant_w<<<NUM_SUB / 256, 256, 0, stream>>>(packed, d, dmin, scales, mins, wb);
    gemm_bt<<<dim3(N_DIM / BN, M_DIM / BM), 256, 0, stream>>>(xb, wb, out);
}

// Round 4
// 317.125 us; speedup vs baseline: 1.3763x; 1.0433x over previous
//
#include <hip/hip_runtime.h>
#include <stdint.h>

// Problem constants (fixed shapes from reference)
#define M_DIM 4096   // 2 * 2048 rows of x
#define K_DIM 4096   // in_features
#define N_DIM 4096   // out_features
#define NUM_SUB (65536 * 8)  // superblocks * 8 subblocks

typedef __bf16 bf16_t;
typedef bf16_t bf16x8 __attribute__((ext_vector_type(8)));
typedef float f32x4 __attribute__((ext_vector_type(4)));

// ---------------------------------------------------------------------------
// Kernel 1: fp32 -> bf16 convert of x (16.7M elements), vectorized 8/thread
// ---------------------------------------------------------------------------
__global__ __launch_bounds__(256) void cvt_x_bf16(const float* __restrict__ x,
                                                  bf16_t* __restrict__ o) {
    size_t i = ((size_t)blockIdx.x * blockDim.x + threadIdx.x) * 8;
    const float4* p = (const float4*)(x + i);
    float4 a = p[0];
    float4 b = p[1];
    bf16x8 v;
    v[0] = (bf16_t)a.x; v[1] = (bf16_t)a.y; v[2] = (bf16_t)a.z; v[3] = (bf16_t)a.w;
    v[4] = (bf16_t)b.x; v[5] = (bf16_t)b.y; v[6] = (bf16_t)b.z; v[7] = (bf16_t)b.w;
    *(bf16x8*)(o + i) = v;
}

// ---------------------------------------------------------------------------
// Kernel 2: Q4_K-style dequant -> bf16 W[N][K].
// w = q * (d*scale/945) + (d*min/63 + dmin)
// ---------------------------------------------------------------------------
__global__ __launch_bounds__(256) void dequant_w(const int* __restrict__ packed,
                                                 const float* __restrict__ d,
                                                 const float* __restrict__ dmin,
                                                 const int* __restrict__ scales,
                                                 const int* __restrict__ mins,
                                                 bf16_t* __restrict__ W) {
    int t = blockIdx.x * blockDim.x + threadIdx.x;   // 0 .. NUM_SUB-1
    int s = t >> 3;                                  // superblock
    float ds = d[s];
    float dm = dmin[s];
    float a = ds * (float)scales[t] * (1.0f / 945.0f);   // 945 = 15*63
    float b = ds * (float)mins[t] * (1.0f / 63.0f) + dm;

    const int4* p4 = (const int4*)(packed + (size_t)t * 16);
    bf16_t outv[32];
#pragma unroll
    for (int c = 0; c < 4; ++c) {
        int4 pv = p4[c];
        int vals[4] = {pv.x, pv.y, pv.z, pv.w};
#pragma unroll
        for (int u = 0; u < 4; ++u) {
            int byte = vals[u];
            float lo = (float)(byte & 15) * a + b;
            float hi = (float)((byte >> 4) & 15) * a + b;
            outv[c * 8 + u * 2]     = (bf16_t)lo;
            outv[c * 8 + u * 2 + 1] = (bf16_t)hi;
        }
    }
    bf16_t* dst = W + (size_t)t * 32;
#pragma unroll
    for (int c = 0; c < 4; ++c)
        ((bf16x8*)dst)[c] = ((const bf16x8*)outv)[c];
}

// ---------------------------------------------------------------------------
// Kernel 3: C[M,N](fp32) = A[M,K](bf16) * B[N,K](bf16)^T
// Round-4: double-buffered LDS + raw-barrier pipeline (vmcnt(4), never 0
// except last iter) + XCD-aware tile swizzle. Keeps round-3's XOR-swizzled
// conflict-free LDS layout and coalesced staging.
//
// Per iter i:  stage tile i+1 -> buf^1 ; s_waitcnt vmcnt(4) (tile i ready,
// tile i+1 still in flight) ; s_barrier ; ds_read frags buf ; MFMA ;
// lgkmcnt(0)+s_barrier (all waves done reading buf before iter i+1's staging
// overwrites it).
// ---------------------------------------------------------------------------
#define BM 128
#define BN 128
#define BK 32

__device__ __forceinline__ void async_copy16(void* lds, const void* g) {
    __builtin_amdgcn_global_load_lds(
        (const __attribute__((address_space(1))) void*)g,
        (__attribute__((address_space(3))) void*)lds, 16, 0, 0);
}

__global__ __launch_bounds__(256) void gemm_bt(const bf16_t* __restrict__ A,
                                               const bf16_t* __restrict__ B,
                                               float* __restrict__ C) {
    __shared__ bf16_t sA[2][BM * BK];   // 2 x 8 KB
    __shared__ bf16_t sB[2][BN * BK];   // 2 x 8 KB

    const int tid  = threadIdx.x;
    const int wave = tid >> 6;
    const int lane = tid & 63;
    const int wm = wave >> 1;
    const int wn = wave & 1;
    const int r = lane & 15;
    const int q = lane >> 4;

    // XCD-aware swizzle: bid%8 = XCD (round-robin dispatch heuristic).
    // Each XCD gets a 16(M) x 8(N) tile patch -> per-k-step L2 slice traffic
    // 24 tiles vs 36 unswizzled. Perf heuristic only (G16-safe).
    const int bid  = blockIdx.x;
    const int xcd  = bid & 7;
    const int slot = bid >> 3;
    const int m0 = (((xcd >> 2) << 4) + (slot & 15)) * BM;
    const int n0 = (((xcd & 3) << 3) + (slot >> 4)) * BN;

    f32x4 acc[4][4] = {};

    // Staging: lane fetches (row = tid>>2, kc = (lane&3) ^ ((lane>>3)&3)).
    const int rowS = tid >> 2;
    const int kcS  = ((lane & 3) ^ ((lane >> 3) & 3)) * 8;
    const bf16_t* gA0 = A + (size_t)(m0 + rowS) * K_DIM + kcS;
    const bf16_t* gA1 = gA0 + (size_t)64 * K_DIM;
    const bf16_t* gB0 = B + (size_t)(n0 + rowS) * K_DIM + kcS;
    const bf16_t* gB1 = gB0 + (size_t)64 * K_DIM;
    const int ldsOff = wave * 512;       // wave-uniform group base (elements)

    // Fragment-read chunk index: c = 4r + (q ^ ((r>>1)&3))  (conflict-free)
    const int fragOff = (4 * r + (q ^ ((r >> 1) & 3))) * 8;

#define STAGE(buf, koff)                                                  \
    do {                                                                  \
        async_copy16(&sA[buf][ldsOff],        gA0 + (koff));              \
        async_copy16(&sA[buf][2048 + ldsOff], gA1 + (koff));              \
        async_copy16(&sB[buf][ldsOff],        gB0 + (koff));              \
        async_copy16(&sB[buf][2048 + ldsOff], gB1 + (koff));              \
    } while (0)

#define COMPUTE(buf)                                                      \
    do {                                                                  \
        bf16x8 af[4], bfr[4];                                             \
        _Pragma("unroll")                                                 \
        for (int t = 0; t < 4; ++t) {                                     \
            af[t]  = *(const bf16x8*)&sA[buf][(wm * 4 + t) * 512 + fragOff]; \
            bfr[t] = *(const bf16x8*)&sB[buf][(wn * 4 + t) * 512 + fragOff]; \
        }                                                                 \
        _Pragma("unroll")                                                 \
        for (int ii = 0; ii < 4; ++ii)                                    \
            _Pragma("unroll")                                             \
            for (int jj = 0; jj < 4; ++jj)                                \
                acc[ii][jj] = __builtin_amdgcn_mfma_f32_16x16x32_bf16(    \
                    af[ii], bfr[jj], acc[ii][jj], 0, 0, 0);               \
    } while (0)

    STAGE(0, 0);                          // prologue: tile 0 -> buf 0

#pragma unroll 2
    for (int i = 0; i < 127; ++i) {
        const int cur = i & 1;
        STAGE(cur ^ 1, (i + 1) * BK);     // tile i+1 in flight across barrier
        asm volatile("s_waitcnt vmcnt(4)" ::: "memory");   // tile i ready
        asm volatile("s_barrier" ::: "memory");
        COMPUTE(cur);
        asm volatile("s_waitcnt lgkmcnt(0)" ::: "memory"); // my reads done
        asm volatile("s_barrier" ::: "memory");            // all reads done
    }
    // last iteration (tile 127 in buf 1)
    asm volatile("s_waitcnt vmcnt(0)" ::: "memory");
    asm volatile("s_barrier" ::: "memory");
    COMPUTE(1);

    // Epilogue: C/D layout col = lane&15, row = (lane>>4)*4 + reg  [m89]
#pragma unroll
    for (int i = 0; i < 4; ++i) {
        int row = m0 + wm * 64 + i * 16 + q * 4;
#pragma unroll
        for (int j = 0; j < 4; ++j) {
            int col = n0 + wn * 64 + j * 16 + r;
#pragma unroll
            for (int reg = 0; reg < 4; ++reg)
                C[(size_t)(row + reg) * N_DIM + col] = acc[i][j][reg];
        }
    }
#undef STAGE
#undef COMPUTE
}

// ---------------------------------------------------------------------------
// Launch: needs 67 MB of d_ws (33.5 MB x-bf16 + 33.5 MB W-bf16).
// ---------------------------------------------------------------------------
extern "C" void kernel_launch(void* const* d_in, const int* in_sizes, int n_in,
                              void* d_out, int out_size, void* d_ws, size_t ws_size,
                              hipStream_t stream) {
    const float* x      = (const float*)d_in[0];
    const int*   packed = (const int*)d_in[1];
    const float* d      = (const float*)d_in[2];
    const float* dmin   = (const float*)d_in[3];
    const int*   scales = (const int*)d_in[4];
    const int*   mins   = (const int*)d_in[5];
    float* out = (float*)d_out;

    bf16_t* xb = (bf16_t*)d_ws;                       // [M_DIM * K_DIM]
    bf16_t* wb = xb + (size_t)M_DIM * K_DIM;          // [N_DIM * K_DIM]

    cvt_x_bf16<<<(M_DIM * (size_t)K_DIM) / (256 * 8), 256, 0, stream>>>(x, xb);
    dequant_w<<<NUM_SUB / 256, 256, 0, stream>>>(packed, d, dmin, scales, mins, wb);
    gemm_bt<<<1024, 256, 0, stream>>>(xb, wb, out);
}

// Round 5
// 247.397 us; speedup vs baseline: 1.7642x; 1.2818x over previous
//
#include <hip/hip_runtime.h>
#include <stdint.h>

// Problem constants (fixed shapes from reference)
#define M_DIM 4096   // 2 * 2048 rows of x
#define K_DIM 4096   // in_features
#define N_DIM 4096   // out_features

typedef float f32x4 __attribute__((ext_vector_type(4)));
typedef int   i32x4 __attribute__((ext_vector_type(4)));

// ---------------------------------------------------------------------------
// Kernel 1: x fp32 -> i8 with per-row scale. One block per row (4096 rows),
// 256 threads x 16 elems. absmax reduce (shuffle + LDS), round-to-nearest.
// ---------------------------------------------------------------------------
__global__ __launch_bounds__(256) void quant_x(const float* __restrict__ x,
                                               int8_t* __restrict__ xq,
                                               float* __restrict__ sx) {
    __shared__ float red[4];
    const int row  = blockIdx.x;
    const int base = threadIdx.x * 16;
    const float* xr = x + (size_t)row * K_DIM + base;
    float4 v[4];
#pragma unroll
    for (int c = 0; c < 4; ++c) v[c] = ((const float4*)xr)[c];
    float am = 0.f;
#pragma unroll
    for (int c = 0; c < 4; ++c) {
        am = fmaxf(am, fabsf(v[c].x)); am = fmaxf(am, fabsf(v[c].y));
        am = fmaxf(am, fabsf(v[c].z)); am = fmaxf(am, fabsf(v[c].w));
    }
#pragma unroll
    for (int off = 32; off; off >>= 1) am = fmaxf(am, __shfl_xor(am, off, 64));
    if ((threadIdx.x & 63) == 0) red[threadIdx.x >> 6] = am;
    __syncthreads();
    float amax = fmaxf(fmaxf(red[0], red[1]), fmaxf(red[2], red[3]));
    amax = fmaxf(amax, 1e-20f);
    const float inv = 127.0f / amax;
    int ow[4];
#pragma unroll
    for (int c = 0; c < 4; ++c) {
        int q0 = __float2int_rn(v[c].x * inv);
        int q1 = __float2int_rn(v[c].y * inv);
        int q2 = __float2int_rn(v[c].z * inv);
        int q3 = __float2int_rn(v[c].w * inv);
        ow[c] = (q0 & 255) | ((q1 & 255) << 8) | ((q2 & 255) << 16) | ((q3 & 255) << 24);
    }
    ((int4*)(xq + (size_t)row * K_DIM + base))[0] = make_int4(ow[0], ow[1], ow[2], ow[3]);
    if (threadIdx.x == 0) sx[row] = amax / 127.0f;
}

// ---------------------------------------------------------------------------
// Kernel 2: Q4_K dequant -> i8 W with per-row scale. One block per W-row.
// Row n = 16 superblocks = 128 subblocks; w = q*a + b, a,b >= 0 so the exact
// row max is max_t(15*a[t] + b[t]). Phase 1: subblock a,b + max-reduce.
// Phase 2: each thread quantizes 16 weights (8 packed int32, one byte each).
// ---------------------------------------------------------------------------
__global__ __launch_bounds__(256) void quant_w(const int* __restrict__ packed,
                                               const float* __restrict__ d,
                                               const float* __restrict__ dmin,
                                               const int* __restrict__ scales,
                                               const int* __restrict__ mins,
                                               int8_t* __restrict__ wq,
                                               float* __restrict__ sw) {
    __shared__ float sa[128], sb[128], red[4];
    const int n = blockIdx.x;
    const int t = threadIdx.x;
    float m = 0.f;
    if (t < 128) {
        int sub  = n * 128 + t;
        int sidx = n * 16 + (t >> 3);
        float dd = d[sidx], dm = dmin[sidx];
        float a = dd * (float)scales[sub] * (1.0f / 945.0f);
        float b = dd * (float)mins[sub] * (1.0f / 63.0f) + dm;
        sa[t] = a; sb[t] = b;
        m = 15.0f * a + b;
    }
#pragma unroll
    for (int off = 32; off; off >>= 1) m = fmaxf(m, __shfl_xor(m, off, 64));
    if ((t & 63) == 0) red[t >> 6] = m;
    __syncthreads();
    float rowmax = fmaxf(fmaxf(red[0], red[1]), fmaxf(red[2], red[3]));
    rowmax = fmaxf(rowmax, 1e-20f);
    const float inv = 127.0f / rowmax;

    const int sub = t >> 1;                    // 16 weights = half a subblock
    const float a = sa[sub] * inv;
    const float b = sb[sub] * inv;
    const int4* p4 = (const int4*)(packed + (size_t)n * (K_DIM / 2) + t * 8);
    int4 pv0 = p4[0], pv1 = p4[1];
    int bytes[8] = {pv0.x, pv0.y, pv0.z, pv0.w, pv1.x, pv1.y, pv1.z, pv1.w};
    int ow[4];
#pragma unroll
    for (int c = 0; c < 4; ++c) {
        int b0 = bytes[2 * c], b1 = bytes[2 * c + 1];
        int q0 = __float2int_rn((float)(b0 & 15) * a + b);
        int q1 = __float2int_rn((float)((b0 >> 4) & 15) * a + b);
        int q2 = __float2int_rn((float)(b1 & 15) * a + b);
        int q3 = __float2int_rn((float)((b1 >> 4) & 15) * a + b);
        ow[c] = (q0 & 255) | ((q1 & 255) << 8) | ((q2 & 255) << 16) | ((q3 & 255) << 24);
    }
    ((int4*)(wq + (size_t)n * K_DIM + t * 16))[0] = make_int4(ow[0], ow[1], ow[2], ow[3]);
    if (t == 0) sw[n] = rowmax / 127.0f;
}

// ---------------------------------------------------------------------------
// Kernel 3: C[M,N](fp32) = sx[m]*sw[n] * (Aq[M,K](i8) . Bq[N,K](i8)^T)
// i8 16x16x64 MFMA, BK=64 (one k-step/iter, 64 iters). Same dbuf raw-barrier
// pipeline and XOR-swizzled conflict-free LDS byte layout as round 4 (chunk
// structure per 16-row group: 64 slots x 16 B — byte-identical pattern).
// ---------------------------------------------------------------------------
#define BM 128
#define BN 128
#define BKB 64    // bytes (i8 elems) of K per iter

__device__ __forceinline__ void async_copy16(void* lds, const void* g) {
    __builtin_amdgcn_global_load_lds(
        (const __attribute__((address_space(1))) void*)g,
        (__attribute__((address_space(3))) void*)lds, 16, 0, 0);
}

__global__ __launch_bounds__(256) void gemm_i8(const int8_t* __restrict__ A,
                                               const int8_t* __restrict__ B,
                                               const float* __restrict__ sx,
                                               const float* __restrict__ sw,
                                               float* __restrict__ C) {
    __shared__ int8_t sAb[2][BM * BKB];   // 2 x 8 KB
    __shared__ int8_t sBb[2][BN * BKB];   // 2 x 8 KB

    const int tid  = threadIdx.x;
    const int wave = tid >> 6;
    const int lane = tid & 63;
    const int wm = wave >> 1;
    const int wn = wave & 1;
    const int r = lane & 15;
    const int q = lane >> 4;

    // XCD-aware swizzle (kept from R4; neutral but harmless)
    const int bid  = blockIdx.x;
    const int xcd  = bid & 7;
    const int slot = bid >> 3;
    const int m0 = (((xcd >> 2) << 4) + (slot & 15)) * BM;
    const int n0 = (((xcd & 3) << 3) + (slot >> 4)) * BN;

    i32x4 acc[4][4] = {};

    // Staging: lane fetches (row = tid>>2, kc = (lane&3)^((lane>>3)&3)) — 4
    // consecutive lanes cover one row's 64 contiguous bytes (coalesced).
    const int rowS = tid >> 2;
    const int kcS  = ((lane & 3) ^ ((lane >> 3) & 3)) * 16;   // bytes
    const int8_t* gA0 = A + (size_t)(m0 + rowS) * K_DIM + kcS;
    const int8_t* gA1 = gA0 + (size_t)64 * K_DIM;
    const int8_t* gB0 = B + (size_t)(n0 + rowS) * K_DIM + kcS;
    const int8_t* gB1 = gB0 + (size_t)64 * K_DIM;
    const int ldsOff = wave * 1024;      // wave-uniform group base (bytes)

    // Fragment read: lane (q,r) wants (row r, kchunk q) -> slot 4r + (q ^ ((r>>1)&3))
    const int fragOff = (4 * r + (q ^ ((r >> 1) & 3))) * 16;  // bytes

#define STAGE(buf, koff)                                                  \
    do {                                                                  \
        async_copy16(&sAb[buf][ldsOff],        gA0 + (koff));             \
        async_copy16(&sAb[buf][4096 + ldsOff], gA1 + (koff));             \
        async_copy16(&sBb[buf][ldsOff],        gB0 + (koff));             \
        async_copy16(&sBb[buf][4096 + ldsOff], gB1 + (koff));             \
    } while (0)

#define COMPUTE(buf)                                                      \
    do {                                                                  \
        i32x4 af[4], bfr[4];                                              \
        _Pragma("unroll")                                                 \
        for (int tt = 0; tt < 4; ++tt) {                                  \
            af[tt]  = *(const i32x4*)&sAb[buf][(wm * 4 + tt) * 1024 + fragOff]; \
            bfr[tt] = *(const i32x4*)&sBb[buf][(wn * 4 + tt) * 1024 + fragOff]; \
        }                                                                 \
        _Pragma("unroll")                                                 \
        for (int ii = 0; ii < 4; ++ii)                                    \
            _Pragma("unroll")                                             \
            for (int jj = 0; jj < 4; ++jj)                                \
                acc[ii][jj] = __builtin_amdgcn_mfma_i32_16x16x64_i8(      \
                    af[ii], bfr[jj], acc[ii][jj], 0, 0, 0);               \
    } while (0)

    STAGE(0, 0);                           // prologue: tile 0 -> buf 0

#pragma unroll 2
    for (int i = 0; i < 63; ++i) {         // 64 k-iters total
        const int cur = i & 1;
        STAGE(cur ^ 1, (i + 1) * BKB);     // tile i+1 in flight across barrier
        asm volatile("s_waitcnt vmcnt(4)" ::: "memory");   // tile i ready
        asm volatile("s_barrier" ::: "memory");
        COMPUTE(cur);
        asm volatile("s_waitcnt lgkmcnt(0)" ::: "memory");
        asm volatile("s_barrier" ::: "memory");
    }
    asm volatile("s_waitcnt vmcnt(0)" ::: "memory");
    asm volatile("s_barrier" ::: "memory");
    COMPUTE(1);                            // tile 63 (odd) is in buf 1

    // Epilogue: C/D layout col = lane&15, row = (lane>>4)*4 + reg  [m89]
    // out = float(acc) * sx[row] * sw[col]
#pragma unroll
    for (int i = 0; i < 4; ++i) {
        int row = m0 + wm * 64 + i * 16 + q * 4;
#pragma unroll
        for (int j = 0; j < 4; ++j) {
            int col = n0 + wn * 64 + j * 16 + r;
            float swc = sw[col];
#pragma unroll
            for (int reg = 0; reg < 4; ++reg)
                C[(size_t)(row + reg) * N_DIM + col] =
                    (float)acc[i][j][reg] * sx[row + reg] * swc;
        }
    }
#undef STAGE
#undef COMPUTE
}

// ---------------------------------------------------------------------------
// Launch: ws usage = 16.7 MB xq + 16.7 MB wq + 32 KB scales.
// ---------------------------------------------------------------------------
extern "C" void kernel_launch(void* const* d_in, const int* in_sizes, int n_in,
                              void* d_out, int out_size, void* d_ws, size_t ws_size,
                              hipStream_t stream) {
    const float* x      = (const float*)d_in[0];
    const int*   packed = (const int*)d_in[1];
    const float* d      = (const float*)d_in[2];
    const float* dmin   = (const float*)d_in[3];
    const int*   scales = (const int*)d_in[4];
    const int*   mins   = (const int*)d_in[5];
    float* out = (float*)d_out;

    int8_t* xq = (int8_t*)d_ws;                               // 16.7 MB
    int8_t* wq = xq + (size_t)M_DIM * K_DIM;                  // 16.7 MB
    float*  sx = (float*)(wq + (size_t)N_DIM * K_DIM);        // 16 KB
    float*  sw = sx + M_DIM;                                  // 16 KB

    quant_x<<<M_DIM, 256, 0, stream>>>(x, xq, sx);
    quant_w<<<N_DIM, 256, 0, stream>>>(packed, d, dmin, scales, mins, wq, sw);
    gemm_i8<<<1024, 256, 0, stream>>>(xq, wq, sx, sw, out);
}